// Round 6
// baseline (169.608 us; speedup 1.0000x reference)
//
#include <hip/hip_runtime.h>
#include <hip/hip_bf16.h>

// Shapes: bz=32, rv_num=10, rv_len=128, in_feat=300, out_feat=128
// N = 320 reviews/side, tokens/side = 40960, M = 1280 tokens/sample.

#define K_FEAT 300
#define H 128
#define NTOK 40960
#define NREV 320
#define TOK_PER_SAMPLE 1280
#define TM 128                      // tokens per fc block
#define BLKS_PER_SAMPLE 10          // 1280/128
#define LDA 40                      // LDS row stride in bf16 (32 k + 8 pad)
#define NCHUNK 10
#define WCHUNK (2 * H * LDA)        // 10240 bf16 per chunk (hi block + lo block)

typedef __attribute__((ext_vector_type(8))) short bf16x8;
typedef __attribute__((ext_vector_type(4))) float f32x4;
typedef unsigned short u16;
typedef unsigned int u32;

static __device__ __forceinline__ u16 f2bf(float x) {
    u32 u = __float_as_uint(x);
    return (u16)((u + 0x7fffu + ((u >> 16) & 1u)) >> 16);
}
static __device__ __forceinline__ float bf2f(u16 s) {
    return __uint_as_float(((u32)s) << 16);
}

// ---------------- Kernel 0: pack W into chunk-major padded bf16 hi/lo ----------------
// Wc[c][part(hi=0,lo=1)][h][kk<40], kk>=32 or k>=300 zero-padded. 102400 elems.
__global__ void wsplit_kernel(const float* __restrict__ W, u16* __restrict__ Wc)
{
    int i = blockIdx.x * 256 + threadIdx.x;
    if (i >= NCHUNK * WCHUNK) return;
    int c = i / WCHUNK;
    int rem = i - c * WCHUNK;
    int part = rem / (H * LDA);
    int rem2 = rem - part * (H * LDA);
    int h = rem2 / LDA;
    int kk = rem2 - h * LDA;
    int k = c * 32 + kk;
    float w = (kk < 32 && k < K_FEAT) ? W[(size_t)k * H + h] : 0.f;
    u16 hi = f2bf(w);
    Wc[i] = part ? f2bf(w - bf2f(hi)) : hi;
}

// ---------------- Kernel 1: FC + ReLU via 3-term split-bf16 MFMA + psum ----------------
// grid.x = 640 (320/side); block = 256 (4 waves). Tile 128 tok x 128 feat.
// Wave w owns n-tiles {2w, 2w+1} x all 8 m-tiles: 48 MFMA / 20 b128 per chunk.
__global__ __launch_bounds__(256, 3) void fc_mfma_kernel(
    const float* __restrict__ seq_a, const float* __restrict__ seq_b,
    const u16* __restrict__ Wc, const float* __restrict__ bias,
    float* __restrict__ ta, float* __restrict__ tb,
    float* __restrict__ psum_a, float* __restrict__ psum_b)
{
    __shared__ u16 Ah_s[TM * LDA];      // 10240 B
    __shared__ u16 Al_s[TM * LDA];      // 10240 B
    __shared__ u16 W_s[WCHUNK];         // 20480 B: [0..5119]=hi, [5120..]=lo
    __shared__ float bias_s[H];

    int blk = blockIdx.x;
    const float* seq; float* outp; float* psum;
    if (blk < 320) { seq = seq_a; outp = ta; psum = psum_a; }
    else           { seq = seq_b; outp = tb; psum = psum_b; blk -= 320; }

    const int tid = threadIdx.x;
    const int tok0 = blk * TM;
    const int wave = tid >> 6;
    const int lane = tid & 63;
    const int nn = lane & 15;
    const int quad = lane >> 4;

    if (tid < H) bias_s[tid] = bias[tid];

    f32x4 acc[8][2];
#pragma unroll
    for (int m = 0; m < 8; ++m) {
        acc[m][0] = (f32x4){0.f, 0.f, 0.f, 0.f};
        acc[m][1] = (f32x4){0.f, 0.f, 0.f, 0.f};
    }

    for (int c = 0; c < NCHUNK; ++c) {
        __syncthreads();
        // Stage A: 128 tok x 32 k fp32 -> bf16 hi + lo. 1024 float4, 4/thread.
#pragma unroll
        for (int it = 0; it < 4; ++it) {
            int i = tid + it * 256;
            int t = i >> 3;
            int j = i & 7;
            int kk = c * 32 + 4 * j;
            float4 v = make_float4(0.f, 0.f, 0.f, 0.f);
            if (kk + 4 <= K_FEAT)
                v = *(const float4*)&seq[(size_t)(tok0 + t) * K_FEAT + kk];
            u16 h0 = f2bf(v.x), h1 = f2bf(v.y), h2 = f2bf(v.z), h3 = f2bf(v.w);
            uint2 hp, lp;
            hp.x = (u32)h0 | ((u32)h1 << 16);
            hp.y = (u32)h2 | ((u32)h3 << 16);
            lp.x = (u32)f2bf(v.x - bf2f(h0)) | ((u32)f2bf(v.y - bf2f(h1)) << 16);
            lp.y = (u32)f2bf(v.z - bf2f(h2)) | ((u32)f2bf(v.w - bf2f(h3)) << 16);
            *(uint2*)&Ah_s[t * LDA + 4 * j] = hp;
            *(uint2*)&Al_s[t * LDA + 4 * j] = lp;
        }
        // Stage W: straight 20 KB copy (chunk-major, pre-padded). 1280 uint4, 5/thread.
        const u16* wsrc = Wc + (size_t)c * WCHUNK;
#pragma unroll
        for (int it = 0; it < 5; ++it) {
            int i = tid + it * 256;
            *(uint4*)&W_s[i * 8] = *(const uint4*)&wsrc[i * 8];
        }
        __syncthreads();

        // B fragments, loaded once per chunk (wave-resident across the m-loop)
        bf16x8 bh0 = *(const bf16x8*)&W_s[((2 * wave + 0) * 16 + nn) * LDA + quad * 8];
        bf16x8 bl0 = *(const bf16x8*)&W_s[5120 + ((2 * wave + 0) * 16 + nn) * LDA + quad * 8];
        bf16x8 bh1 = *(const bf16x8*)&W_s[((2 * wave + 1) * 16 + nn) * LDA + quad * 8];
        bf16x8 bl1 = *(const bf16x8*)&W_s[5120 + ((2 * wave + 1) * 16 + nn) * LDA + quad * 8];
#pragma unroll
        for (int m = 0; m < 8; ++m) {
            bf16x8 a_hi = *(const bf16x8*)&Ah_s[(m * 16 + nn) * LDA + quad * 8];
            bf16x8 a_lo = *(const bf16x8*)&Al_s[(m * 16 + nn) * LDA + quad * 8];
            acc[m][0] = __builtin_amdgcn_mfma_f32_16x16x32_bf16(a_hi, bh0, acc[m][0], 0, 0, 0);
            acc[m][0] = __builtin_amdgcn_mfma_f32_16x16x32_bf16(a_hi, bl0, acc[m][0], 0, 0, 0);
            acc[m][0] = __builtin_amdgcn_mfma_f32_16x16x32_bf16(a_lo, bh0, acc[m][0], 0, 0, 0);
            acc[m][1] = __builtin_amdgcn_mfma_f32_16x16x32_bf16(a_hi, bh1, acc[m][1], 0, 0, 0);
            acc[m][1] = __builtin_amdgcn_mfma_f32_16x16x32_bf16(a_hi, bl1, acc[m][1], 0, 0, 0);
            acc[m][1] = __builtin_amdgcn_mfma_f32_16x16x32_bf16(a_lo, bh1, acc[m][1], 0, 0, 0);
        }
    }

    // Epilogue: bias + ReLU + fp32 store; per-feature block sums via wave shuffle.
    // C/D layout: col = nn -> feature, row = quad*4+reg -> token within m-tile.
#pragma unroll
    for (int t2 = 0; t2 < 2; ++t2) {
        int hcol = (2 * wave + t2) * 16 + nn;
        float bv = bias_s[hcol];
        float fs = 0.f;
#pragma unroll
        for (int m = 0; m < 8; ++m) {
#pragma unroll
            for (int reg = 0; reg < 4; ++reg) {
                int tok = tok0 + m * 16 + quad * 4 + reg;
                float v = fmaxf(acc[m][t2][reg] + bv, 0.f);
                outp[(size_t)tok * H + hcol] = v;
                fs += v;
            }
        }
        fs += __shfl_xor(fs, 16);
        fs += __shfl_xor(fs, 32);
        if (quad == 0) psum[(size_t)blk * H + hcol] = fs;
    }
}

// ---------------- Kernel 2: scores -> masked softmax -> weighted sum ----------------
// R4-proven version: score partials via padded LDS table; phase 3 re-reads the
// (L2/L3-hot) tile from global. grid.x = 640; block = 256.
__global__ __launch_bounds__(256) void attn_kernel(
    const float* __restrict__ ta, const float* __restrict__ tb,
    const int* __restrict__ mask_a, const int* __restrict__ mask_b,
    const float* __restrict__ psum_a, const float* __restrict__ psum_b,
    float* __restrict__ out)
{
    int n = blockIdx.x;
    int side = 0;
    if (n >= NREV) { side = 1; n -= NREV; }

    const float* t = side ? tb : ta;
    const int* mask = side ? mask_b : mask_a;
    const float* psum_o = side ? psum_a : psum_b;   // partial sums of the OTHER side
    float* out_vec = out + (side ? NREV * H : 0);
    float* out_w = out + 2 * NREV * H + (side ? NREV * H : 0);

    int sample = n / 10;
    int tid = threadIdx.x;

    __shared__ float score_part[128 * 33];
    __shared__ float mean_s[128];
    __shared__ float w_s[128];
    __shared__ float red[4];
    __shared__ float part_out[8 * 128];

    if (tid < 128) {
        float s = 0.f;
        const float* pb = psum_o + (size_t)sample * BLKS_PER_SAMPLE * H + tid;
#pragma unroll
        for (int i = 0; i < BLKS_PER_SAMPLE; ++i) s += pb[(size_t)i * H];
        mean_s[tid] = s * (1.0f / (float)TOK_PER_SAMPLE);
    }
    __syncthreads();

    const float* rowbase = t + (size_t)n * 128 * H;

    // Phase 1: streaming score partials (coalesced float4 over the 128x128 tile)
#pragma unroll
    for (int i = 0; i < 16; ++i) {
        int q = tid + 256 * i;
        int r = q >> 5;
        int c4 = q & 31;
        float4 v = *(const float4*)&rowbase[q * 4];
        float4 m = *(const float4*)&mean_s[c4 * 4];
        score_part[r * 33 + c4] = v.x * m.x + v.y * m.y + v.z * m.z + v.w * m.w;
    }
    __syncthreads();

    // Phase 2: row sums -> masked softmax
    float logit = -1e9f;
    if (tid < 128) {
        float s = 0.f;
#pragma unroll
        for (int j = 0; j < 32; ++j) s += score_part[tid * 33 + j];
        int mv = mask[n * 128 + tid];
        logit = (mv > 0) ? s : -1e9f;
    }

    float mx = logit;
    for (int off = 32; off > 0; off >>= 1) mx = fmaxf(mx, __shfl_xor(mx, off));
    if ((tid & 63) == 0) red[tid >> 6] = mx;
    __syncthreads();
    mx = fmaxf(fmaxf(red[0], red[1]), fmaxf(red[2], red[3]));
    __syncthreads();

    float e = __expf(logit - mx);
    float ssum = e;
    for (int off = 32; off > 0; off >>= 1) ssum += __shfl_xor(ssum, off);
    if ((tid & 63) == 0) red[tid >> 6] = ssum;
    __syncthreads();
    ssum = red[0] + red[1] + red[2] + red[3];

    float w = e / ssum;
    if (tid < 128) {
        w_s[tid] = w;
        out_w[n * 128 + tid] = w;
    }
    __syncthreads();

    // Phase 3: out[d] = sum_l w_l * row_l[d] (rows L2/L3-hot)
    int c4 = tid & 31;
    int lp = tid >> 5;
    float4 o4 = make_float4(0.f, 0.f, 0.f, 0.f);
#pragma unroll
    for (int k = 0; k < 16; ++k) {
        int l = k * 8 + lp;
        float wl = w_s[l];
        float4 v = *(const float4*)&rowbase[(size_t)l * H + c4 * 4];
        o4.x = fmaf(wl, v.x, o4.x);
        o4.y = fmaf(wl, v.y, o4.y);
        o4.z = fmaf(wl, v.z, o4.z);
        o4.w = fmaf(wl, v.w, o4.w);
    }
    *(float4*)&part_out[lp * 128 + c4 * 4] = o4;
    __syncthreads();
    if (tid < 128) {
        float o = 0.f;
#pragma unroll
        for (int p = 0; p < 8; ++p) o += part_out[p * 128 + tid];
        out_vec[n * 128 + tid] = o;
    }
}

// ---------------- Launch ----------------
extern "C" void kernel_launch(void* const* d_in, const int* in_sizes, int n_in,
                              void* d_out, int out_size, void* d_ws, size_t ws_size,
                              hipStream_t stream)
{
    const float* seq_a = (const float*)d_in[0];
    const float* seq_b = (const float*)d_in[1];
    const int* mask_a = (const int*)d_in[2];
    const int* mask_b = (const int*)d_in[3];
    const float* W = (const float*)d_in[4];
    const float* bias = (const float*)d_in[5];
    float* out = (float*)d_out;

    float* ws = (float*)d_ws;
    float* ta = ws;                                   // 40960*128 f32
    float* tb = ta + (size_t)NTOK * H;                // 40960*128 f32
    float* psum_a = tb + (size_t)NTOK * H;            // 320*128
    float* psum_b = psum_a + NREV * H;                // 320*128
    u16* Wc = (u16*)(psum_b + NREV * H);              // 102400 bf16

    wsplit_kernel<<<(NCHUNK * WCHUNK + 255) / 256, 256, 0, stream>>>(W, Wc);
    fc_mfma_kernel<<<640, 256, 0, stream>>>(seq_a, seq_b, Wc, bias, ta, tb, psum_a, psum_b);
    attn_kernel<<<640, 256, 0, stream>>>(ta, tb, mask_a, mask_b, psum_a, psum_b, out);
}

// Round 7
// 163.593 us; speedup vs baseline: 1.0368x; 1.0368x over previous
//
#include <hip/hip_runtime.h>
#include <hip/hip_bf16.h>

// Shapes: bz=32, rv_num=10, rv_len=128, in_feat=300, out_feat=128
// N = 320 reviews/side, tokens/side = 40960, M = 1280 tokens/sample.

#define K_FEAT 300
#define H 128
#define NTOK 40960
#define NREV 320
#define TOK_PER_SAMPLE 1280
#define TM 128                      // tokens per fc block
#define BLKS_PER_SAMPLE 10          // 1280/128
#define LDA 40                      // LDS row stride in bf16 (32 k + 8 pad)
#define NCHUNK 10
#define WFRAG_ELEMS (NCHUNK * 4 * 4 * 64 * 8)   // 81920 bf16 = 160 KB

typedef __attribute__((ext_vector_type(8))) short bf16x8;
typedef __attribute__((ext_vector_type(4))) float f32x4;
typedef unsigned short u16;
typedef unsigned int u32;

static __device__ __forceinline__ u16 f2bf(float x) {
    u32 u = __float_as_uint(x);
    return (u16)((u + 0x7fffu + ((u >> 16) & 1u)) >> 16);
}
static __device__ __forceinline__ float bf2f(u16 s) {
    return __uint_as_float(((u32)s) << 16);
}

// ---------------- Kernel 0: pack W into per-(chunk,wave,frag,lane) bf16 fragments ----------
// Wfrag[c][wave][frag][lane][8]; frag = t2*2 + part (part 0=hi, 1=lo).
// h = (2*wave + t2)*16 + (lane&15); k = c*32 + (lane>>4)*8 + j; zero-pad k >= 300.
__global__ void wsplit_kernel(const float* __restrict__ W, u16* __restrict__ Wfrag)
{
    int i = blockIdx.x * 256 + threadIdx.x;
    if (i >= WFRAG_ELEMS) return;
    int j    = i & 7;
    int lane = (i >> 3) & 63;
    int frag = (i >> 9) & 3;
    int wave = (i >> 11) & 3;
    int c    = i >> 13;
    int nn = lane & 15, quad = lane >> 4;
    int t2 = frag >> 1, part = frag & 1;
    int h = (2 * wave + t2) * 16 + nn;
    int k = c * 32 + quad * 8 + j;
    float w = (k < K_FEAT) ? W[(size_t)k * H + h] : 0.f;
    u16 hi = f2bf(w);
    Wfrag[i] = part ? f2bf(w - bf2f(hi)) : hi;
}

// ---------------- Kernel 1: FC + ReLU, 3-term split-bf16 MFMA, pipelined ----------------
// grid.x = 640 (320/side); block = 256 (4 waves). Tile 128 tok x 128 feat.
// W fragments read direct from global (L2-hot); A(c+1) loads issued before MFMA(c).
__global__ __launch_bounds__(256, 3) void fc_mfma_kernel(
    const float* __restrict__ seq_a, const float* __restrict__ seq_b,
    const u16* __restrict__ Wfrag, const float* __restrict__ bias,
    float* __restrict__ ta, float* __restrict__ tb,
    float* __restrict__ psum_a, float* __restrict__ psum_b)
{
    __shared__ u16 Ah_s[TM * LDA];      // 10240 B
    __shared__ u16 Al_s[TM * LDA];      // 10240 B
    __shared__ float bias_s[H];

    int blk = blockIdx.x;
    const float* seq; float* outp; float* psum;
    if (blk < 320) { seq = seq_a; outp = ta; psum = psum_a; }
    else           { seq = seq_b; outp = tb; psum = psum_b; blk -= 320; }

    const int tid = threadIdx.x;
    const int tok0 = blk * TM;
    const int wave = tid >> 6;
    const int lane = tid & 63;
    const int nn = lane & 15;
    const int quad = lane >> 4;

    if (tid < H) bias_s[tid] = bias[tid];

    // Per-thread staging coords: thread handles tokens t = tid>>3, float4 j = tid&7 (x4 iters)
    const int st_t = tid >> 3;          // base token index / 4 groups of 32 tokens
    const int st_j = tid & 7;

    f32x4 acc[8][2];
#pragma unroll
    for (int m = 0; m < 8; ++m) {
        acc[m][0] = (f32x4){0.f, 0.f, 0.f, 0.f};
        acc[m][1] = (f32x4){0.f, 0.f, 0.f, 0.f};
    }

    float4 pf[4];
    // prologue: load + store chunk 0
#pragma unroll
    for (int it = 0; it < 4; ++it) {
        int t = st_t + it * 32;
        int kk = 4 * st_j;
        pf[it] = make_float4(0.f, 0.f, 0.f, 0.f);
        if (kk + 4 <= K_FEAT)
            pf[it] = *(const float4*)&seq[(size_t)(tok0 + t) * K_FEAT + kk];
    }
#pragma unroll
    for (int it = 0; it < 4; ++it) {
        int t = st_t + it * 32;
        float4 v = pf[it];
        u16 h0 = f2bf(v.x), h1 = f2bf(v.y), h2 = f2bf(v.z), h3 = f2bf(v.w);
        uint2 hp, lp;
        hp.x = (u32)h0 | ((u32)h1 << 16);
        hp.y = (u32)h2 | ((u32)h3 << 16);
        lp.x = (u32)f2bf(v.x - bf2f(h0)) | ((u32)f2bf(v.y - bf2f(h1)) << 16);
        lp.y = (u32)f2bf(v.z - bf2f(h2)) | ((u32)f2bf(v.w - bf2f(h3)) << 16);
        *(uint2*)&Ah_s[t * LDA + 4 * st_j] = hp;
        *(uint2*)&Al_s[t * LDA + 4 * st_j] = lp;
    }
    __syncthreads();

    for (int c = 0; c < NCHUNK; ++c) {
        // Issue A loads for chunk c+1 (latency hidden behind MFMA loop below)
        if (c < NCHUNK - 1) {
#pragma unroll
            for (int it = 0; it < 4; ++it) {
                int t = st_t + it * 32;
                int kk = (c + 1) * 32 + 4 * st_j;
                pf[it] = make_float4(0.f, 0.f, 0.f, 0.f);
                if (kk + 4 <= K_FEAT)
                    pf[it] = *(const float4*)&seq[(size_t)(tok0 + t) * K_FEAT + kk];
            }
        }
        // W fragments for chunk c: direct coalesced global loads (L2-resident)
        const u16* wf = Wfrag + (size_t)(c * 4 + wave) * 2048;
        bf16x8 bh0 = *(const bf16x8*)&wf[0 * 512 + lane * 8];
        bf16x8 bl0 = *(const bf16x8*)&wf[1 * 512 + lane * 8];
        bf16x8 bh1 = *(const bf16x8*)&wf[2 * 512 + lane * 8];
        bf16x8 bl1 = *(const bf16x8*)&wf[3 * 512 + lane * 8];
#pragma unroll
        for (int m = 0; m < 8; ++m) {
            bf16x8 a_hi = *(const bf16x8*)&Ah_s[(m * 16 + nn) * LDA + quad * 8];
            bf16x8 a_lo = *(const bf16x8*)&Al_s[(m * 16 + nn) * LDA + quad * 8];
            acc[m][0] = __builtin_amdgcn_mfma_f32_16x16x32_bf16(a_hi, bh0, acc[m][0], 0, 0, 0);
            acc[m][0] = __builtin_amdgcn_mfma_f32_16x16x32_bf16(a_hi, bl0, acc[m][0], 0, 0, 0);
            acc[m][0] = __builtin_amdgcn_mfma_f32_16x16x32_bf16(a_lo, bh0, acc[m][0], 0, 0, 0);
            acc[m][1] = __builtin_amdgcn_mfma_f32_16x16x32_bf16(a_hi, bh1, acc[m][1], 0, 0, 0);
            acc[m][1] = __builtin_amdgcn_mfma_f32_16x16x32_bf16(a_hi, bl1, acc[m][1], 0, 0, 0);
            acc[m][1] = __builtin_amdgcn_mfma_f32_16x16x32_bf16(a_lo, bh1, acc[m][1], 0, 0, 0);
        }
        __syncthreads();   // all waves done READING chunk c from LDS
        if (c < NCHUNK - 1) {
#pragma unroll
            for (int it = 0; it < 4; ++it) {
                int t = st_t + it * 32;
                float4 v = pf[it];
                u16 h0 = f2bf(v.x), h1 = f2bf(v.y), h2 = f2bf(v.z), h3 = f2bf(v.w);
                uint2 hp, lp;
                hp.x = (u32)h0 | ((u32)h1 << 16);
                hp.y = (u32)h2 | ((u32)h3 << 16);
                lp.x = (u32)f2bf(v.x - bf2f(h0)) | ((u32)f2bf(v.y - bf2f(h1)) << 16);
                lp.y = (u32)f2bf(v.z - bf2f(h2)) | ((u32)f2bf(v.w - bf2f(h3)) << 16);
                *(uint2*)&Ah_s[t * LDA + 4 * st_j] = hp;
                *(uint2*)&Al_s[t * LDA + 4 * st_j] = lp;
            }
            __syncthreads();   // chunk c+1 staged before anyone reads
        }
    }

    // Epilogue: bias + ReLU + fp32 store; per-feature block sums via wave shuffle.
    // C/D layout: col = nn -> feature, row = quad*4+reg -> token within m-tile.
#pragma unroll
    for (int t2 = 0; t2 < 2; ++t2) {
        int hcol = (2 * wave + t2) * 16 + nn;
        float bv = bias_s[hcol];
        float fs = 0.f;
#pragma unroll
        for (int m = 0; m < 8; ++m) {
#pragma unroll
            for (int reg = 0; reg < 4; ++reg) {
                int tok = tok0 + m * 16 + quad * 4 + reg;
                float v = fmaxf(acc[m][t2][reg] + bv, 0.f);
                outp[(size_t)tok * H + hcol] = v;
                fs += v;
            }
        }
        fs += __shfl_xor(fs, 16);
        fs += __shfl_xor(fs, 32);
        if (quad == 0) psum[(size_t)blk * H + hcol] = fs;
    }
}

// ---------------- Kernel 2: scores -> masked softmax -> weighted sum (R4/R6-proven) ----------
__global__ __launch_bounds__(256) void attn_kernel(
    const float* __restrict__ ta, const float* __restrict__ tb,
    const int* __restrict__ mask_a, const int* __restrict__ mask_b,
    const float* __restrict__ psum_a, const float* __restrict__ psum_b,
    float* __restrict__ out)
{
    int n = blockIdx.x;
    int side = 0;
    if (n >= NREV) { side = 1; n -= NREV; }

    const float* t = side ? tb : ta;
    const int* mask = side ? mask_b : mask_a;
    const float* psum_o = side ? psum_a : psum_b;   // partial sums of the OTHER side
    float* out_vec = out + (side ? NREV * H : 0);
    float* out_w = out + 2 * NREV * H + (side ? NREV * H : 0);

    int sample = n / 10;
    int tid = threadIdx.x;

    __shared__ float score_part[128 * 33];
    __shared__ float mean_s[128];
    __shared__ float w_s[128];
    __shared__ float red[4];
    __shared__ float part_out[8 * 128];

    if (tid < 128) {
        float s = 0.f;
        const float* pb = psum_o + (size_t)sample * BLKS_PER_SAMPLE * H + tid;
#pragma unroll
        for (int i = 0; i < BLKS_PER_SAMPLE; ++i) s += pb[(size_t)i * H];
        mean_s[tid] = s * (1.0f / (float)TOK_PER_SAMPLE);
    }
    __syncthreads();

    const float* rowbase = t + (size_t)n * 128 * H;

    // Phase 1: streaming score partials (coalesced float4 over the 128x128 tile)
#pragma unroll
    for (int i = 0; i < 16; ++i) {
        int q = tid + 256 * i;
        int r = q >> 5;
        int c4 = q & 31;
        float4 v = *(const float4*)&rowbase[q * 4];
        float4 m = *(const float4*)&mean_s[c4 * 4];
        score_part[r * 33 + c4] = v.x * m.x + v.y * m.y + v.z * m.z + v.w * m.w;
    }
    __syncthreads();

    // Phase 2: row sums -> masked softmax
    float logit = -1e9f;
    if (tid < 128) {
        float s = 0.f;
#pragma unroll
        for (int j = 0; j < 32; ++j) s += score_part[tid * 33 + j];
        int mv = mask[n * 128 + tid];
        logit = (mv > 0) ? s : -1e9f;
    }

    float mx = logit;
    for (int off = 32; off > 0; off >>= 1) mx = fmaxf(mx, __shfl_xor(mx, off));
    if ((tid & 63) == 0) red[tid >> 6] = mx;
    __syncthreads();
    mx = fmaxf(fmaxf(red[0], red[1]), fmaxf(red[2], red[3]));
    __syncthreads();

    float e = __expf(logit - mx);
    float ssum = e;
    for (int off = 32; off > 0; off >>= 1) ssum += __shfl_xor(ssum, off);
    if ((tid & 63) == 0) red[tid >> 6] = ssum;
    __syncthreads();
    ssum = red[0] + red[1] + red[2] + red[3];

    float w = e / ssum;
    if (tid < 128) {
        w_s[tid] = w;
        out_w[n * 128 + tid] = w;
    }
    __syncthreads();

    // Phase 3: out[d] = sum_l w_l * row_l[d] (rows L2/L3-hot)
    int c4 = tid & 31;
    int lp = tid >> 5;
    float4 o4 = make_float4(0.f, 0.f, 0.f, 0.f);
#pragma unroll
    for (int k = 0; k < 16; ++k) {
        int l = k * 8 + lp;
        float wl = w_s[l];
        float4 v = *(const float4*)&rowbase[(size_t)l * H + c4 * 4];
        o4.x = fmaf(wl, v.x, o4.x);
        o4.y = fmaf(wl, v.y, o4.y);
        o4.z = fmaf(wl, v.z, o4.z);
        o4.w = fmaf(wl, v.w, o4.w);
    }
    *(float4*)&part_out[lp * 128 + c4 * 4] = o4;
    __syncthreads();
    if (tid < 128) {
        float o = 0.f;
#pragma unroll
        for (int p = 0; p < 8; ++p) o += part_out[p * 128 + tid];
        out_vec[n * 128 + tid] = o;
    }
}

// ---------------- Launch ----------------
extern "C" void kernel_launch(void* const* d_in, const int* in_sizes, int n_in,
                              void* d_out, int out_size, void* d_ws, size_t ws_size,
                              hipStream_t stream)
{
    const float* seq_a = (const float*)d_in[0];
    const float* seq_b = (const float*)d_in[1];
    const int* mask_a = (const int*)d_in[2];
    const int* mask_b = (const int*)d_in[3];
    const float* W = (const float*)d_in[4];
    const float* bias = (const float*)d_in[5];
    float* out = (float*)d_out;

    float* ws = (float*)d_ws;
    float* ta = ws;                                   // 40960*128 f32
    float* tb = ta + (size_t)NTOK * H;                // 40960*128 f32
    float* psum_a = tb + (size_t)NTOK * H;            // 320*128
    float* psum_b = psum_a + NREV * H;                // 320*128
    u16* Wfrag = (u16*)(psum_b + NREV * H);           // 81920 bf16

    wsplit_kernel<<<(WFRAG_ELEMS + 255) / 256, 256, 0, stream>>>(W, Wfrag);
    fc_mfma_kernel<<<640, 256, 0, stream>>>(seq_a, seq_b, Wfrag, bias, ta, tb, psum_a, psum_b);
    attn_kernel<<<640, 256, 0, stream>>>(ta, tb, mask_a, mask_b, psum_a, psum_b, out);
}

// Round 8
// 162.027 us; speedup vs baseline: 1.0468x; 1.0097x over previous
//
#include <hip/hip_runtime.h>
#include <hip/hip_bf16.h>

// Shapes: bz=32, rv_num=10, rv_len=128, in_feat=300, out_feat=128
// N = 320 reviews/side, tokens/side = 40960, M = 1280 tokens/sample.

#define K_FEAT 300
#define H 128
#define NTOK 40960
#define NREV 320
#define TOK_PER_SAMPLE 1280
#define TM 128                      // tokens per fc block
#define BLKS_PER_SAMPLE 10          // 1280/128
#define LDA 40                      // LDS row stride in bf16 (32 k + 8 pad)
#define NCHUNK 10
#define WFRAG_ELEMS (NCHUNK * 4 * 4 * 64 * 8)   // 81920 bf16 = 160 KB

typedef __attribute__((ext_vector_type(8))) short bf16x8;
typedef __attribute__((ext_vector_type(4))) float f32x4;
typedef unsigned short u16;
typedef unsigned int u32;

static __device__ __forceinline__ u16 f2bf(float x) {
    u32 u = __float_as_uint(x);
    return (u16)((u + 0x7fffu + ((u >> 16) & 1u)) >> 16);
}
static __device__ __forceinline__ float bf2f(u16 s) {
    return __uint_as_float(((u32)s) << 16);
}

// ---------------- Kernel 0: pack W into per-(chunk,wave,frag,lane) bf16 fragments ----------
// Wfrag[c][wave][frag][lane][8]; frag = t2*2 + part (part 0=hi, 1=lo).
// h = (2*wave + t2)*16 + (lane&15); k = c*32 + (lane>>4)*8 + j; zero-pad k >= 300.
__global__ void wsplit_kernel(const float* __restrict__ W, u16* __restrict__ Wfrag)
{
    int i = blockIdx.x * 256 + threadIdx.x;
    if (i >= WFRAG_ELEMS) return;
    int j    = i & 7;
    int lane = (i >> 3) & 63;
    int frag = (i >> 9) & 3;
    int wave = (i >> 11) & 3;
    int c    = i >> 13;
    int nn = lane & 15, quad = lane >> 4;
    int t2 = frag >> 1, part = frag & 1;
    int h = (2 * wave + t2) * 16 + nn;
    int k = c * 32 + quad * 8 + j;
    float w = (k < K_FEAT) ? W[(size_t)k * H + h] : 0.f;
    u16 hi = f2bf(w);
    Wfrag[i] = part ? f2bf(w - bf2f(hi)) : hi;
}

// ---------------- Kernel 1: FC + ReLU, 3-term split-bf16 MFMA, bf16 output ----------------
// grid.x = 640 (320/side); block = 256 (4 waves). Tile 128 tok x 128 feat.
// Swapped operands: D = mfma(Wfrag, Afrag) -> D rows = h (quad*4+reg), cols = tok (nn).
// Epilogue: packed 8B bf16 stores; psum via in-wave shuffle (no atomics anywhere).
__global__ __launch_bounds__(256, 3) void fc_mfma_kernel(
    const float* __restrict__ seq_a, const float* __restrict__ seq_b,
    const u16* __restrict__ Wfrag, const float* __restrict__ bias,
    u16* __restrict__ ta, u16* __restrict__ tb,
    float* __restrict__ psum_a, float* __restrict__ psum_b)
{
    __shared__ u16 Ah_s[TM * LDA];      // 10240 B
    __shared__ u16 Al_s[TM * LDA];      // 10240 B
    __shared__ float bias_s[H];

    int blk = blockIdx.x;
    const float* seq; u16* outp; float* psum;
    if (blk < 320) { seq = seq_a; outp = ta; psum = psum_a; }
    else           { seq = seq_b; outp = tb; psum = psum_b; blk -= 320; }

    const int tid = threadIdx.x;
    const int tok0 = blk * TM;
    const int wave = tid >> 6;
    const int lane = tid & 63;
    const int nn = lane & 15;
    const int quad = lane >> 4;

    if (tid < H) bias_s[tid] = bias[tid];

    const int st_t = tid >> 3;          // staging: token base, float4 index
    const int st_j = tid & 7;

    f32x4 acc[8][2];                    // [tok-tile][h-tile]
#pragma unroll
    for (int m = 0; m < 8; ++m) {
        acc[m][0] = (f32x4){0.f, 0.f, 0.f, 0.f};
        acc[m][1] = (f32x4){0.f, 0.f, 0.f, 0.f};
    }

    float4 pf[4];
    // prologue: load + convert + store chunk 0
#pragma unroll
    for (int it = 0; it < 4; ++it) {
        int t = st_t + it * 32;
        int kk = 4 * st_j;
        pf[it] = make_float4(0.f, 0.f, 0.f, 0.f);
        if (kk + 4 <= K_FEAT)
            pf[it] = *(const float4*)&seq[(size_t)(tok0 + t) * K_FEAT + kk];
    }
#pragma unroll
    for (int it = 0; it < 4; ++it) {
        int t = st_t + it * 32;
        float4 v = pf[it];
        u16 h0 = f2bf(v.x), h1 = f2bf(v.y), h2 = f2bf(v.z), h3 = f2bf(v.w);
        uint2 hp, lp;
        hp.x = (u32)h0 | ((u32)h1 << 16);
        hp.y = (u32)h2 | ((u32)h3 << 16);
        lp.x = (u32)f2bf(v.x - bf2f(h0)) | ((u32)f2bf(v.y - bf2f(h1)) << 16);
        lp.y = (u32)f2bf(v.z - bf2f(h2)) | ((u32)f2bf(v.w - bf2f(h3)) << 16);
        *(uint2*)&Ah_s[t * LDA + 4 * st_j] = hp;
        *(uint2*)&Al_s[t * LDA + 4 * st_j] = lp;
    }
    __syncthreads();

    for (int c = 0; c < NCHUNK; ++c) {
        // Issue A loads for chunk c+1 (latency hidden behind MFMA loop)
        if (c < NCHUNK - 1) {
#pragma unroll
            for (int it = 0; it < 4; ++it) {
                int t = st_t + it * 32;
                int kk = (c + 1) * 32 + 4 * st_j;
                pf[it] = make_float4(0.f, 0.f, 0.f, 0.f);
                if (kk + 4 <= K_FEAT)
                    pf[it] = *(const float4*)&seq[(size_t)(tok0 + t) * K_FEAT + kk];
            }
        }
        // W fragments for chunk c: direct coalesced global loads (L2-resident)
        const u16* wf = Wfrag + (size_t)(c * 4 + wave) * 2048;
        bf16x8 bh0 = *(const bf16x8*)&wf[0 * 512 + lane * 8];
        bf16x8 bl0 = *(const bf16x8*)&wf[1 * 512 + lane * 8];
        bf16x8 bh1 = *(const bf16x8*)&wf[2 * 512 + lane * 8];
        bf16x8 bl1 = *(const bf16x8*)&wf[3 * 512 + lane * 8];
#pragma unroll
        for (int m = 0; m < 8; ++m) {
            bf16x8 a_hi = *(const bf16x8*)&Ah_s[(m * 16 + nn) * LDA + quad * 8];
            bf16x8 a_lo = *(const bf16x8*)&Al_s[(m * 16 + nn) * LDA + quad * 8];
            // swapped: D[h][tok]
            acc[m][0] = __builtin_amdgcn_mfma_f32_16x16x32_bf16(bh0, a_hi, acc[m][0], 0, 0, 0);
            acc[m][0] = __builtin_amdgcn_mfma_f32_16x16x32_bf16(bl0, a_hi, acc[m][0], 0, 0, 0);
            acc[m][0] = __builtin_amdgcn_mfma_f32_16x16x32_bf16(bh0, a_lo, acc[m][0], 0, 0, 0);
            acc[m][1] = __builtin_amdgcn_mfma_f32_16x16x32_bf16(bh1, a_hi, acc[m][1], 0, 0, 0);
            acc[m][1] = __builtin_amdgcn_mfma_f32_16x16x32_bf16(bl1, a_hi, acc[m][1], 0, 0, 0);
            acc[m][1] = __builtin_amdgcn_mfma_f32_16x16x32_bf16(bh1, a_lo, acc[m][1], 0, 0, 0);
        }
        __syncthreads();   // all waves done READING chunk c from LDS
        if (c < NCHUNK - 1) {
#pragma unroll
            for (int it = 0; it < 4; ++it) {
                int t = st_t + it * 32;
                float4 v = pf[it];
                u16 h0 = f2bf(v.x), h1 = f2bf(v.y), h2 = f2bf(v.z), h3 = f2bf(v.w);
                uint2 hp, lp;
                hp.x = (u32)h0 | ((u32)h1 << 16);
                hp.y = (u32)h2 | ((u32)h3 << 16);
                lp.x = (u32)f2bf(v.x - bf2f(h0)) | ((u32)f2bf(v.y - bf2f(h1)) << 16);
                lp.y = (u32)f2bf(v.z - bf2f(h2)) | ((u32)f2bf(v.w - bf2f(h3)) << 16);
                *(uint2*)&Ah_s[t * LDA + 4 * st_j] = hp;
                *(uint2*)&Al_s[t * LDA + 4 * st_j] = lp;
            }
            __syncthreads();   // chunk c+1 staged before anyone reads
        }
    }

    // Epilogue (swapped layout): lane holds h = (2*wave+ht)*16 + quad*4 + reg, tok = tok0+tt*16+nn.
#pragma unroll
    for (int ht = 0; ht < 2; ++ht) {
        int h0 = (2 * wave + ht) * 16 + quad * 4;
        float4 bb = *(const float4*)&bias_s[h0];
        float fs[4] = {0.f, 0.f, 0.f, 0.f};
#pragma unroll
        for (int tt = 0; tt < 8; ++tt) {
            int tok = tok0 + tt * 16 + nn;
            float v0 = fmaxf(acc[tt][ht][0] + bb.x, 0.f);
            float v1 = fmaxf(acc[tt][ht][1] + bb.y, 0.f);
            float v2 = fmaxf(acc[tt][ht][2] + bb.z, 0.f);
            float v3 = fmaxf(acc[tt][ht][3] + bb.w, 0.f);
            fs[0] += v0; fs[1] += v1; fs[2] += v2; fs[3] += v3;
            uint2 p;
            p.x = (u32)f2bf(v0) | ((u32)f2bf(v1) << 16);
            p.y = (u32)f2bf(v2) | ((u32)f2bf(v3) << 16);
            *(uint2*)&outp[(size_t)tok * H + h0] = p;
        }
        // reduce over nn (16 tokens per tile x 8 tiles = all 128 tokens of the block)
#pragma unroll
        for (int r = 0; r < 4; ++r) {
            fs[r] += __shfl_xor(fs[r], 1);
            fs[r] += __shfl_xor(fs[r], 2);
            fs[r] += __shfl_xor(fs[r], 4);
            fs[r] += __shfl_xor(fs[r], 8);
        }
        if (nn == 0) {
#pragma unroll
            for (int r = 0; r < 4; ++r)
                psum[(size_t)blk * H + h0 + r] = fs[r];
        }
    }
}

// ---------------- Kernel 2: scores -> masked softmax -> weighted sum (bf16 tiles) ----------
// grid.x = 640; block = 256. R4-proven structure, tile dtype bf16.
__global__ __launch_bounds__(256) void attn_kernel(
    const u16* __restrict__ ta, const u16* __restrict__ tb,
    const int* __restrict__ mask_a, const int* __restrict__ mask_b,
    const float* __restrict__ psum_a, const float* __restrict__ psum_b,
    float* __restrict__ out)
{
    int n = blockIdx.x;
    int side = 0;
    if (n >= NREV) { side = 1; n -= NREV; }

    const u16* t = side ? tb : ta;
    const int* mask = side ? mask_b : mask_a;
    const float* psum_o = side ? psum_a : psum_b;   // partial sums of the OTHER side
    float* out_vec = out + (side ? NREV * H : 0);
    float* out_w = out + 2 * NREV * H + (side ? NREV * H : 0);

    int sample = n / 10;
    int tid = threadIdx.x;

    __shared__ float score_part[128 * 17];  // [row][col-group-of-8], padded
    __shared__ float mean_s[128];
    __shared__ float w_s[128];
    __shared__ float red[4];
    __shared__ float part_out[16 * 128];

    if (tid < 128) {
        float s = 0.f;
        const float* pb = psum_o + (size_t)sample * BLKS_PER_SAMPLE * H + tid;
#pragma unroll
        for (int i = 0; i < BLKS_PER_SAMPLE; ++i) s += pb[(size_t)i * H];
        mean_s[tid] = s * (1.0f / (float)TOK_PER_SAMPLE);
    }
    __syncthreads();

    const u16* rowbase = t + (size_t)n * 128 * H;

    // Phase 1: streaming score partials; uint4 = 8 bf16 per load, coalesced.
#pragma unroll
    for (int i = 0; i < 8; ++i) {
        int q = tid + 256 * i;          // 0..2047
        int r = q >> 4;                 // row
        int c8 = q & 15;                // group of 8 features
        uint4 v = *(const uint4*)&rowbase[r * H + c8 * 8];
        const float* m = &mean_s[c8 * 8];
        float p = 0.f;
        p += bf2f((u16)(v.x & 0xffff)) * m[0];
        p += bf2f((u16)(v.x >> 16)) * m[1];
        p += bf2f((u16)(v.y & 0xffff)) * m[2];
        p += bf2f((u16)(v.y >> 16)) * m[3];
        p += bf2f((u16)(v.z & 0xffff)) * m[4];
        p += bf2f((u16)(v.z >> 16)) * m[5];
        p += bf2f((u16)(v.w & 0xffff)) * m[6];
        p += bf2f((u16)(v.w >> 16)) * m[7];
        score_part[r * 17 + c8] = p;
    }
    __syncthreads();

    // Phase 2: row sums -> masked softmax
    float logit = -1e9f;
    if (tid < 128) {
        float s = 0.f;
#pragma unroll
        for (int j = 0; j < 16; ++j) s += score_part[tid * 17 + j];
        int mv = mask[n * 128 + tid];
        logit = (mv > 0) ? s : -1e9f;
    }

    float mx = logit;
    for (int off = 32; off > 0; off >>= 1) mx = fmaxf(mx, __shfl_xor(mx, off));
    if ((tid & 63) == 0) red[tid >> 6] = mx;
    __syncthreads();
    mx = fmaxf(fmaxf(red[0], red[1]), fmaxf(red[2], red[3]));
    __syncthreads();

    float e = __expf(logit - mx);
    float ssum = e;
    for (int off = 32; off > 0; off >>= 1) ssum += __shfl_xor(ssum, off);
    if ((tid & 63) == 0) red[tid >> 6] = ssum;
    __syncthreads();
    ssum = red[0] + red[1] + red[2] + red[3];

    float w = e / ssum;
    if (tid < 128) {
        w_s[tid] = w;
        out_w[n * 128 + tid] = w;
    }
    __syncthreads();

    // Phase 3: out[d] = sum_l w_l * row_l[d] (rows L2-hot, bf16)
    int c8 = tid & 15;   // 8 features
    int lp = tid >> 4;   // 16 l-partitions
    float o[8] = {0.f, 0.f, 0.f, 0.f, 0.f, 0.f, 0.f, 0.f};
#pragma unroll
    for (int k = 0; k < 8; ++k) {
        int l = k * 16 + lp;
        float wl = w_s[l];
        uint4 v = *(const uint4*)&rowbase[l * H + c8 * 8];
        o[0] = fmaf(wl, bf2f((u16)(v.x & 0xffff)), o[0]);
        o[1] = fmaf(wl, bf2f((u16)(v.x >> 16)), o[1]);
        o[2] = fmaf(wl, bf2f((u16)(v.y & 0xffff)), o[2]);
        o[3] = fmaf(wl, bf2f((u16)(v.y >> 16)), o[3]);
        o[4] = fmaf(wl, bf2f((u16)(v.z & 0xffff)), o[4]);
        o[5] = fmaf(wl, bf2f((u16)(v.z >> 16)), o[5]);
        o[6] = fmaf(wl, bf2f((u16)(v.w & 0xffff)), o[6]);
        o[7] = fmaf(wl, bf2f((u16)(v.w >> 16)), o[7]);
    }
    *(float4*)&part_out[lp * 128 + c8 * 8] = make_float4(o[0], o[1], o[2], o[3]);
    *(float4*)&part_out[lp * 128 + c8 * 8 + 4] = make_float4(o[4], o[5], o[6], o[7]);
    __syncthreads();
    if (tid < 128) {
        float s = 0.f;
#pragma unroll
        for (int p = 0; p < 16; ++p) s += part_out[p * 128 + tid];
        out_vec[n * 128 + tid] = s;
    }
}

// ---------------- Launch ----------------
extern "C" void kernel_launch(void* const* d_in, const int* in_sizes, int n_in,
                              void* d_out, int out_size, void* d_ws, size_t ws_size,
                              hipStream_t stream)
{
    const float* seq_a = (const float*)d_in[0];
    const float* seq_b = (const float*)d_in[1];
    const int* mask_a = (const int*)d_in[2];
    const int* mask_b = (const int*)d_in[3];
    const float* W = (const float*)d_in[4];
    const float* bias = (const float*)d_in[5];
    float* out = (float*)d_out;

    u16* ta = (u16*)d_ws;                             // 40960*128 bf16
    u16* tb = ta + (size_t)NTOK * H;                  // 40960*128 bf16
    float* psum_a = (float*)(tb + (size_t)NTOK * H);  // 320*128 f32
    float* psum_b = psum_a + NREV * H;                // 320*128 f32
    u16* Wfrag = (u16*)(psum_b + NREV * H);           // 81920 bf16

    wsplit_kernel<<<(WFRAG_ELEMS + 255) / 256, 256, 0, stream>>>(W, Wfrag);
    fc_mfma_kernel<<<640, 256, 0, stream>>>(seq_a, seq_b, Wfrag, bias, ta, tb, psum_a, psum_b);
    attn_kernel<<<640, 256, 0, stream>>>(ta, tb, mask_a, mask_b, psum_a, psum_b, out);
}